// Round 3
// baseline (530.591 us; speedup 1.0000x reference)
//
#include <hip/hip_runtime.h>
#include <stdint.h>

#define NROW 8192
#define IN_F 512
#define OUT_F 64
#define ALPHA 0.2f

// Static device scratch (fully rewritten every call).
__device__ float  g_f1[NROW];
__device__ float  g_f2[NROW];
__device__ float  g_E2f[NROW];   // (float)exp(f2)
__device__ float  g_F2f[NROW];   // (float)exp(0.2*f2)
__device__ double g_E2d[NROW];   // exp(f2)
__device__ double g_F2d[NROW];   // exp(0.2*f2)
__device__ double g_G1[NROW];    // exp(f1)/Z
__device__ double g_H1[NROW];    // exp(0.2*f1)/Z
__device__ double g_colsum[NROW];
__device__ unsigned long long g_mask[(size_t)NROW * 128]; // 8 MB bitmask

// K1 (fused prep_wa + compute_f + colsum-zero), grid 2048 x 256.
// Each block redundantly computes wa1/wa2 = W@a1, W@a2 into LDS (fp64 accum,
// rounded to f32 — identical numerics to the previous two-kernel version; W is
// 128 KB and stays L2-hot), then its 4 waves compute f1/f2 for 4 rows and the
// exp tables. Also zeroes g_colsum (safe: kernel C runs later in stream order).
__global__ void __launch_bounds__(256) setup_kernel(const float* __restrict__ in,
                                                    const float* __restrict__ W,
                                                    const float* __restrict__ a) {
    __shared__ float swa1[IN_F];
    __shared__ float swa2[IN_F];
    int tid = threadIdx.x;
    #pragma unroll
    for (int kk = 0; kk < 2; ++kk) {
        int k = tid + kk * 256;
        double s1 = 0.0, s2 = 0.0;
        for (int t = 0; t < OUT_F; t += 4) {
            float4 w = *(const float4*)&W[k * OUT_F + t];
            // a[t..] is wave-uniform -> scalar loads
            s1 += (double)w.x * (double)a[t]     + (double)w.y * (double)a[t + 1]
                + (double)w.z * (double)a[t + 2] + (double)w.w * (double)a[t + 3];
            s2 += (double)w.x * (double)a[OUT_F + t]     + (double)w.y * (double)a[OUT_F + t + 1]
                + (double)w.z * (double)a[OUT_F + t + 2] + (double)w.w * (double)a[OUT_F + t + 3];
        }
        swa1[k] = (float)s1;
        swa2[k] = (float)s2;
    }
    if (tid < 4) g_colsum[blockIdx.x * 4 + tid] = 0.0;
    __syncthreads();

    int wave = tid >> 6, lane = tid & 63;
    int row = blockIdx.x * 4 + wave;
    const float4* in4  = (const float4*)(in + (size_t)row * IN_F);
    const float4* wa14 = (const float4*)swa1;
    const float4* wa24 = (const float4*)swa2;
    double s1 = 0.0, s2 = 0.0;
    #pragma unroll
    for (int half = 0; half < 2; ++half) {
        int idx = half * 64 + lane;
        float4 x = in4[idx];
        float4 u = wa14[idx];
        float4 v = wa24[idx];
        s1 += (double)x.x*u.x + (double)x.y*u.y + (double)x.z*u.z + (double)x.w*u.w;
        s2 += (double)x.x*v.x + (double)x.y*v.y + (double)x.z*v.z + (double)x.w*v.w;
    }
    #pragma unroll
    for (int off = 32; off > 0; off >>= 1) {
        s1 += __shfl_down(s1, off, 64);
        s2 += __shfl_down(s2, off, 64);
    }
    if (lane == 0) {
        float f1 = (float)s1, f2 = (float)s2;
        g_f1[row] = f1; g_f2[row] = f2;
        double e2 = exp((double)f2), g2 = exp(0.2 * (double)f2);
        g_E2d[row] = e2;        g_F2d[row] = g2;
        g_E2f[row] = (float)e2; g_F2f[row] = (float)g2;
    }
}

// K2 (fused row_z_mask + prep_gh): the single 268 MB pass over adj. Per row i:
//   accp = sum_{adj, f1+f2>0} exp(f2[j]), accn = sum_{adj, else} exp(0.2 f2[j]),
// packs adj into the bitmask, then the tail computes G1 = exp(f1)/Z and
// H1 = exp(0.2 f1)/Z with Z = exp(f1)*accp + exp(0.2 f1)*accn.
// Sign test in the loop via monotone F2[j] > exp(-0.2 f1) — no exp per element.
__global__ void __launch_bounds__(256) row_z_mask(const int* __restrict__ adj) {
    __shared__ float E2s[NROW];   // 32 KB
    __shared__ float F2s[NROW];   // 32 KB
    __shared__ double zp[16], zn[16];
    int tid = threadIdx.x;
    int wave = tid >> 6, lane = tid & 63;
    for (int k = tid; k < NROW / 4; k += 256) {
        ((float4*)E2s)[k] = ((const float4*)g_E2f)[k];
        ((float4*)F2s)[k] = ((const float4*)g_F2f)[k];
    }
    __syncthreads();
    int row0 = blockIdx.x * 4;
    for (int r = 0; r < 4; ++r) {
        int row = row0 + r;
        float f1r = g_f1[row];
        float Ft = expf(-0.2f * f1r);   // pos  <=>  F2[j] > Ft
        const int4* arow = (const int4*)(adj + (size_t)row * NROW) + wave * 512;
        unsigned long long myword = 0;
        double accp = 0.0, accn = 0.0;
        #pragma unroll
        for (int it = 0; it < 8; ++it) {
            int4 av = arow[it * 64 + lane];
            int colbase = wave * 2048 + it * 256 + lane * 4;
            float4 E2v = *(const float4*)&E2s[colbase];
            float4 F2v = *(const float4*)&F2s[colbase];
            bool p0 = av.x > 0, p1 = av.y > 0, p2 = av.z > 0, p3 = av.w > 0;
            unsigned long long b0 = __ballot(p0), b1 = __ballot(p1);
            unsigned long long b2 = __ballot(p2), b3 = __ballot(p3);
            int bl = it * 4;
            if (lane == bl)     myword = b0;
            if (lane == bl + 1) myword = b1;
            if (lane == bl + 2) myword = b2;
            if (lane == bl + 3) myword = b3;
            bool q0 = F2v.x > Ft, q1 = F2v.y > Ft, q2 = F2v.z > Ft, q3 = F2v.w > Ft;
            accp += (p0 && q0) ? (double)E2v.x : 0.0;
            accn += (p0 && !q0) ? (double)F2v.x : 0.0;
            accp += (p1 && q1) ? (double)E2v.y : 0.0;
            accn += (p1 && !q1) ? (double)F2v.y : 0.0;
            accp += (p2 && q2) ? (double)E2v.z : 0.0;
            accn += (p2 && !q2) ? (double)F2v.z : 0.0;
            accp += (p3 && q3) ? (double)E2v.w : 0.0;
            accn += (p3 && !q3) ? (double)F2v.w : 0.0;
        }
        if (lane < 32) g_mask[(size_t)row * 128 + wave * 32 + lane] = myword;
        #pragma unroll
        for (int off = 32; off > 0; off >>= 1) {
            accp += __shfl_down(accp, off, 64);
            accn += __shfl_down(accn, off, 64);
        }
        if (lane == 0) { zp[r * 4 + wave] = accp; zn[r * 4 + wave] = accn; }
    }
    __syncthreads();
    if (tid < 4) {
        int row = row0 + tid;
        double accp = zp[tid*4+0] + zp[tid*4+1] + zp[tid*4+2] + zp[tid*4+3];
        double accn = zn[tid*4+0] + zn[tid*4+1] + zn[tid*4+2] + zn[tid*4+3];
        double f1d = (double)g_f1[row];
        double e1 = exp(f1d), h1 = exp(0.2 * f1d);
        double zinv = 1.0 / (e1 * accp + h1 * accn);
        g_G1[row] = e1 * zinv;
        g_H1[row] = h1 * zinv;
    }
}

// K3: sig_scores[j] += E2d[j]*sum_{i: adj,pos} G1[i] + F2d[j]*sum_{i: adj,neg} H1[i]
// over a 256-row chunk per block. fp32 sign test matches the reference exactly.
__global__ void __launch_bounds__(256) colsum_kernel() {
    __shared__ float  f1s[256];
    __shared__ double G1s[256], H1s[256];
    __shared__ unsigned long long msk[1024];
    int tid = threadIdx.x;
    int cb = blockIdx.x & 31;
    int rb = blockIdx.x >> 5;
    int j = cb * 256 + tid;
    float f2j = g_f2[j];
    int i0 = rb * 256;
    f1s[tid] = g_f1[i0 + tid];
    G1s[tid] = g_G1[i0 + tid];
    H1s[tid] = g_H1[i0 + tid];
    for (int t = tid; t < 1024; t += 256)
        msk[t] = g_mask[(size_t)(i0 + (t >> 2)) * 128 + cb * 4 + (t & 3)];
    __syncthreads();
    int c = tid & 3, bit = (tid >> 2) & 63;
    double accp = 0.0, accn = 0.0;
    for (int i = 0; i < 256; ++i) {
        unsigned long long wv = msk[i * 4 + c];
        bool b = (wv >> bit) & 1ULL;
        float e = f1s[i] + f2j;
        bool pos = e > 0.0f;
        accp += (b && pos)  ? G1s[i] : 0.0;
        accn += (b && !pos) ? H1s[i] : 0.0;
    }
    double res = g_E2d[j] * accp + g_F2d[j] * accn;
    atomicAdd(&g_colsum[j], res);
}

// K4: exact top-K, lax.top_k tie semantics (unchanged — twice verified absmax 0).
__global__ void __launch_bounds__(1024) topk_kernel(int* __restrict__ out, int K) {
    __shared__ unsigned int sbits[NROW];
    __shared__ unsigned int hist[256];
    __shared__ unsigned long long cand[1024];
    __shared__ unsigned long long s_prefix;
    __shared__ unsigned int s_want, s_cnt;
    int tid = threadIdx.x;
    for (int k = tid; k < NROW; k += 1024) {
        float s = (float)g_colsum[k];
        unsigned int u = __float_as_uint(s);
        u = (u & 0x80000000u) ? ~u : (u | 0x80000000u);
        sbits[k] = u;
    }
    if (tid == 0) { s_prefix = 0ULL; s_want = (unsigned)K; s_cnt = 0; }
    __syncthreads();
    for (int lvl = 0; lvl < 6; ++lvl) {
        int shift = 40 - lvl * 8;
        if (tid < 256) hist[tid] = 0;
        __syncthreads();
        unsigned long long pmask = (lvl == 0) ? 0ULL : (~0ULL << (shift + 8));
        unsigned long long prefix = s_prefix;
        for (int k = tid; k < NROW; k += 1024) {
            unsigned long long kk =
                ((unsigned long long)sbits[k] << 13) | (unsigned long long)(8191 - k);
            if ((kk & pmask) == prefix)
                atomicAdd(&hist[(unsigned)(kk >> shift) & 255u], 1u);
        }
        __syncthreads();
        if (tid == 0) {
            unsigned cum = 0; int b = 255;
            for (; b >= 0; --b) { cum += hist[b]; if (cum >= s_want) break; }
            if (b < 0) b = 0;
            s_want -= (cum - hist[b]);
            s_prefix |= ((unsigned long long)b << shift);
        }
        __syncthreads();
    }
    unsigned long long thr = s_prefix;
    for (int k = tid; k < NROW; k += 1024) {
        unsigned long long kk =
            ((unsigned long long)sbits[k] << 13) | (unsigned long long)(8191 - k);
        if (kk >= thr) {
            unsigned pos = atomicAdd(&s_cnt, 1u);
            if (pos < 1024u) cand[pos] = kk;
        }
    }
    __syncthreads();
    unsigned cnt = s_cnt;
    if ((unsigned)tid >= cnt) cand[tid] = 0ULL;
    __syncthreads();
    for (int k2 = 2; k2 <= 1024; k2 <<= 1) {
        for (int jj = k2 >> 1; jj > 0; jj >>= 1) {
            int ixj = tid ^ jj;
            if (ixj > tid) {
                unsigned long long a = cand[tid], b = cand[ixj];
                bool up = ((tid & k2) == 0);
                if (up ? (a < b) : (a > b)) { cand[tid] = b; cand[ixj] = a; }
            }
            __syncthreads();
        }
    }
    if (tid < K) out[tid] = 8191 - (int)(cand[tid] & 0x1FFFULL);
}

extern "C" void kernel_launch(void* const* d_in, const int* in_sizes, int n_in,
                              void* d_out, int out_size, void* d_ws, size_t ws_size,
                              hipStream_t stream) {
    const float* input = (const float*)d_in[0];
    const int*   adj   = (const int*)d_in[1];
    const float* W     = (const float*)d_in[2];
    const float* a     = (const float*)d_in[3];
    int* out = (int*)d_out;
    int K = out_size; // 512

    setup_kernel<<<NROW / 4, 256, 0, stream>>>(input, W, a);
    row_z_mask<<<NROW / 4, 256, 0, stream>>>(adj);
    colsum_kernel<<<1024, 256, 0, stream>>>();
    topk_kernel<<<1, 1024, 0, stream>>>(out, K);
}

// Round 4
// 513.658 us; speedup vs baseline: 1.0330x; 1.0330x over previous
//
#include <hip/hip_runtime.h>
#include <stdint.h>

#define NROW 8192
#define IN_F 512
#define OUT_F 64
#define ALPHA 0.2f

// Static device scratch (fully rewritten every call).
__device__ float  g_wa1[IN_F];
__device__ float  g_wa2[IN_F];
__device__ float  g_f1[NROW];
__device__ float  g_f2[NROW];
__device__ float  g_F2f[NROW];   // (float)exp(0.2*f2)
__device__ double g_E2d[NROW];   // exp(f2)
__device__ double g_F2d[NROW];   // exp(0.2*f2)
__device__ float4 g_pk[NROW];    // {f1, G1=exp(f1)/Z, H1=exp(0.2 f1)/Z, 0}
__device__ double g_colsum[NROW];
__device__ unsigned long long g_mask[(size_t)NROW * 128]; // 8 MB bitmask

// K0: wa1 = W@a1, wa2 = W@a2 (fp64 accum); zero column sums.
__global__ void prep_wa(const float* __restrict__ W, const float* __restrict__ a) {
    int k = threadIdx.x;
    if (k < IN_F) {
        double s1 = 0.0, s2 = 0.0;
        for (int t = 0; t < OUT_F; ++t) {
            double w = (double)W[k * OUT_F + t];
            s1 += w * (double)a[t];
            s2 += w * (double)a[OUT_F + t];
        }
        g_wa1[k] = (float)s1;
        g_wa2[k] = (float)s2;
        #pragma unroll
        for (int i = 0; i < 16; ++i) g_colsum[k * 16 + i] = 0.0;
    }
}

// K1: f1/f2 per row (fp64 accum) + exp tables. One wave per row.
__global__ void __launch_bounds__(256) compute_f(const float* __restrict__ in) {
    int wave = threadIdx.x >> 6, lane = threadIdx.x & 63;
    int row = blockIdx.x * 4 + wave;
    const float4* in4  = (const float4*)(in + (size_t)row * IN_F);
    const float4* wa14 = (const float4*)g_wa1;
    const float4* wa24 = (const float4*)g_wa2;
    double s1 = 0.0, s2 = 0.0;
    #pragma unroll
    for (int half = 0; half < 2; ++half) {
        int idx = half * 64 + lane;
        float4 x = in4[idx];
        float4 u = wa14[idx];
        float4 v = wa24[idx];
        s1 += (double)x.x*u.x + (double)x.y*u.y + (double)x.z*u.z + (double)x.w*u.w;
        s2 += (double)x.x*v.x + (double)x.y*v.y + (double)x.z*v.z + (double)x.w*v.w;
    }
    #pragma unroll
    for (int off = 32; off > 0; off >>= 1) {
        s1 += __shfl_down(s1, off, 64);
        s2 += __shfl_down(s2, off, 64);
    }
    if (lane == 0) {
        float f1 = (float)s1, f2 = (float)s2;
        g_f1[row] = f1; g_f2[row] = f2;
        double e2 = exp((double)f2), g2 = exp(0.2 * (double)f2);
        g_E2d[row] = e2; g_F2d[row] = g2;
        g_F2f[row] = (float)g2;
    }
}

// K2: the single 268 MB pass over adj. Per row i:
//   accp = sum_{adj, f1+f2>0} exp(f2[j]), accn = sum_{adj, else} exp(0.2 f2[j]),
// packs adj into the bitmask; tail computes G1 = exp(f1)/Z, H1 = exp(0.2 f1)/Z.
// Only F2 = exp(0.2 f2) is staged in LDS (32 KB -> 4 blocks/CU); E2 = F2^5.
// Sign test via monotone F2[j] > exp(-0.2 f1) (boundary-safe: both branch
// values coincide at f1+f2=0).
__global__ void __launch_bounds__(256) row_z_mask(const int* __restrict__ adj) {
    __shared__ float F2s[NROW];   // 32 KB
    __shared__ double zp[16], zn[16];
    int tid = threadIdx.x;
    int wave = tid >> 6, lane = tid & 63;
    for (int k = tid; k < NROW / 4; k += 256)
        ((float4*)F2s)[k] = ((const float4*)g_F2f)[k];
    __syncthreads();
    int row0 = blockIdx.x * 4;
    for (int r = 0; r < 4; ++r) {
        int row = row0 + r;
        float f1r = g_f1[row];
        float Ft = expf(-0.2f * f1r);   // pos  <=>  F2[j] > Ft
        const int4* arow = (const int4*)(adj + (size_t)row * NROW) + wave * 512;
        unsigned long long myword = 0;
        double accp = 0.0, accn = 0.0;
        #pragma unroll
        for (int it = 0; it < 8; ++it) {
            int4 av = arow[it * 64 + lane];
            int colbase = wave * 2048 + it * 256 + lane * 4;
            float4 F2v = *(const float4*)&F2s[colbase];
            bool p0 = av.x > 0, p1 = av.y > 0, p2 = av.z > 0, p3 = av.w > 0;
            unsigned long long b0 = __ballot(p0), b1 = __ballot(p1);
            unsigned long long b2 = __ballot(p2), b3 = __ballot(p3);
            int bl = it * 4;
            if (lane == bl)     myword = b0;
            if (lane == bl + 1) myword = b1;
            if (lane == bl + 2) myword = b2;
            if (lane == bl + 3) myword = b3;
            float x2, e;
            bool q0 = F2v.x > Ft, q1 = F2v.y > Ft, q2 = F2v.z > Ft, q3 = F2v.w > Ft;
            x2 = F2v.x * F2v.x; e = x2 * x2 * F2v.x;
            accp += (p0 && q0)  ? (double)e     : 0.0;
            accn += (p0 && !q0) ? (double)F2v.x : 0.0;
            x2 = F2v.y * F2v.y; e = x2 * x2 * F2v.y;
            accp += (p1 && q1)  ? (double)e     : 0.0;
            accn += (p1 && !q1) ? (double)F2v.y : 0.0;
            x2 = F2v.z * F2v.z; e = x2 * x2 * F2v.z;
            accp += (p2 && q2)  ? (double)e     : 0.0;
            accn += (p2 && !q2) ? (double)F2v.z : 0.0;
            x2 = F2v.w * F2v.w; e = x2 * x2 * F2v.w;
            accp += (p3 && q3)  ? (double)e     : 0.0;
            accn += (p3 && !q3) ? (double)F2v.w : 0.0;
        }
        if (lane < 32) g_mask[(size_t)row * 128 + wave * 32 + lane] = myword;
        #pragma unroll
        for (int off = 32; off > 0; off >>= 1) {
            accp += __shfl_down(accp, off, 64);
            accn += __shfl_down(accn, off, 64);
        }
        if (lane == 0) { zp[r * 4 + wave] = accp; zn[r * 4 + wave] = accn; }
    }
    __syncthreads();
    if (tid < 4) {
        int row = row0 + tid;
        double accp = zp[tid*4+0] + zp[tid*4+1] + zp[tid*4+2] + zp[tid*4+3];
        double accn = zn[tid*4+0] + zn[tid*4+1] + zn[tid*4+2] + zn[tid*4+3];
        float f1 = g_f1[row];
        double f1d = (double)f1;
        double e1 = exp(f1d), h1 = exp(0.2 * f1d);
        double zinv = 1.0 / (e1 * accp + h1 * accn);
        g_pk[row] = make_float4(f1, (float)(e1 * zinv), (float)(h1 * zinv), 0.0f);
    }
}

// K3: sig_scores[j] += E2d[j]*sum_{i: adj,pos} G1[i] + F2d[j]*sum_{i: adj,neg} H1[i]
// over a 256-row chunk per block. One float4 broadcast read per row; f32
// partial sums (positive terms, rel err ~1e-6), f64 combine + atomic.
// fp32 sign test f1+f2j>0 matches the reference exactly.
__global__ void __launch_bounds__(256) colsum_kernel() {
    __shared__ float4 pks[256];                 // {f1, G1, H1, 0}
    __shared__ unsigned long long msk[1024];
    int tid = threadIdx.x;
    int cb = blockIdx.x & 31;
    int rb = blockIdx.x >> 5;
    int j = cb * 256 + tid;
    float f2j = g_f2[j];
    int i0 = rb * 256;
    pks[tid] = g_pk[i0 + tid];
    for (int t = tid; t < 1024; t += 256)
        msk[t] = g_mask[(size_t)(i0 + (t >> 2)) * 128 + cb * 4 + (t & 3)];
    __syncthreads();
    int c = tid & 3, bit = (tid >> 2) & 63;
    float accp = 0.0f, accn = 0.0f;
    for (int i = 0; i < 256; ++i) {
        unsigned long long wv = msk[i * 4 + c];
        float4 P = pks[i];
        bool b = (wv >> bit) & 1ULL;
        bool pos = (P.x + f2j) > 0.0f;
        accp += (b && pos)  ? P.y : 0.0f;
        accn += (b && !pos) ? P.z : 0.0f;
    }
    double res = g_E2d[j] * (double)accp + g_F2d[j] * (double)accn;
    atomicAdd(&g_colsum[j], res);
}

// K4: exact top-K, lax.top_k tie semantics. Radix-select over 45-bit keys
// (monotonic f32 bits << 13 | (8191-idx)), with: global AND/OR prefix to skip
// constant bytes, warp-aggregated histogram (one LDS atomic per distinct byte
// per wave), padded per-wave hist banks, uniform redundant scan.
__global__ void __launch_bounds__(1024) topk_kernel(int* __restrict__ out, int K) {
    __shared__ unsigned int sbits[NROW];              // 32 KB
    __shared__ unsigned int shist[16 * 257];          // 16.4 KB padded per-wave hist
    __shared__ unsigned int ctot[256];
    __shared__ unsigned long long wand[16], wor[16];
    __shared__ unsigned long long cand[1024];
    __shared__ unsigned int s_cnt;
    int tid = threadIdx.x;
    int wave = tid >> 6, lane = tid & 63;

    unsigned long long kand = ~0ULL, kor = 0ULL;
    for (int k = tid; k < NROW; k += 1024) {
        float s = (float)g_colsum[k];
        unsigned int u = __float_as_uint(s);
        u = (u & 0x80000000u) ? ~u : (u | 0x80000000u);
        sbits[k] = u;
        unsigned long long kk =
            ((unsigned long long)u << 13) | (unsigned long long)(8191 - k);
        kand &= kk; kor |= kk;
    }
    #pragma unroll
    for (int off = 32; off > 0; off >>= 1) {
        kand &= __shfl_down(kand, off, 64);
        kor  |= __shfl_down(kor,  off, 64);
    }
    if (lane == 0) { wand[wave] = kand; wor[wave] = kor; }
    if (tid == 0) s_cnt = 0;
    __syncthreads();
    unsigned long long andR = ~0ULL, orR = 0ULL;
    #pragma unroll
    for (int w = 0; w < 16; ++w) { andR &= wand[w]; orR |= wor[w]; }
    unsigned long long diff = andR ^ orR;

    unsigned long long prefix = 0ULL;
    unsigned int want = (unsigned)K;
    for (int lvl = 0; lvl < 6; ++lvl) {
        int shift = 40 - lvl * 8;
        unsigned int bdiff = (unsigned)(diff >> shift) & 255u;
        if (bdiff == 0u) {   // byte constant across ALL keys -> no histogram
            prefix |= ((andR >> shift) & 255ULL) << shift;
            continue;
        }
        __syncthreads();
        for (int t = tid; t < 16 * 257; t += 1024) shist[t] = 0;
        __syncthreads();
        unsigned long long pmask = (lvl == 0) ? 0ULL : (~0ULL << (shift + 8));
        for (int k = tid; k < NROW; k += 1024) {
            unsigned long long kk =
                ((unsigned long long)sbits[k] << 13) | (unsigned long long)(8191 - k);
            bool act = (kk & pmask) == (prefix & pmask);
            unsigned int b = (unsigned)(kk >> shift) & 255u;
            unsigned long long am = __ballot(act);
            while (am) {
                int src = __ffsll((long long)am) - 1;
                unsigned int bb = (unsigned)__shfl((int)b, src, 64);
                unsigned long long grp = __ballot(act && (b == bb));
                if (lane == src)
                    atomicAdd(&shist[wave * 257 + bb], (unsigned)__popcll(grp));
                am &= ~grp;
            }
        }
        __syncthreads();
        if (tid < 256) {
            unsigned int s = 0;
            #pragma unroll
            for (int w = 0; w < 16; ++w) s += shist[w * 257 + tid];
            ctot[tid] = s;
        }
        __syncthreads();
        // uniform redundant top-down scan
        unsigned int cum = 0; int b = 255;
        for (; b >= 0; --b) { cum += ctot[b]; if (cum >= want) break; }
        if (b < 0) b = 0;
        want -= (cum - ctot[b]);
        prefix |= ((unsigned long long)b << shift);
    }

    unsigned long long thr = prefix;   // exact K-th largest key (keys unique)
    __syncthreads();
    for (int k = tid; k < NROW; k += 1024) {
        unsigned long long kk =
            ((unsigned long long)sbits[k] << 13) | (unsigned long long)(8191 - k);
        if (kk >= thr) {
            unsigned pos = atomicAdd(&s_cnt, 1u);
            if (pos < 1024u) cand[pos] = kk;
        }
    }
    __syncthreads();
    unsigned cnt = s_cnt;
    if ((unsigned)tid >= cnt) cand[tid] = 0ULL;
    __syncthreads();
    for (int k2 = 2; k2 <= 1024; k2 <<= 1) {
        for (int jj = k2 >> 1; jj > 0; jj >>= 1) {
            int ixj = tid ^ jj;
            if (ixj > tid) {
                unsigned long long a = cand[tid], bb = cand[ixj];
                bool up = ((tid & k2) == 0);
                if (up ? (a < bb) : (a > bb)) { cand[tid] = bb; cand[ixj] = a; }
            }
            __syncthreads();
        }
    }
    if (tid < K) out[tid] = 8191 - (int)(cand[tid] & 0x1FFFULL);
}

extern "C" void kernel_launch(void* const* d_in, const int* in_sizes, int n_in,
                              void* d_out, int out_size, void* d_ws, size_t ws_size,
                              hipStream_t stream) {
    const float* input = (const float*)d_in[0];
    const int*   adj   = (const int*)d_in[1];
    const float* W     = (const float*)d_in[2];
    const float* a     = (const float*)d_in[3];
    int* out = (int*)d_out;
    int K = out_size; // 512

    prep_wa<<<1, 512, 0, stream>>>(W, a);
    compute_f<<<NROW / 4, 256, 0, stream>>>(input);
    row_z_mask<<<NROW / 4, 256, 0, stream>>>(adj);
    colsum_kernel<<<1024, 256, 0, stream>>>();
    topk_kernel<<<1, 1024, 0, stream>>>(out, K);
}